// Round 1
// baseline (403.427 us; speedup 1.0000x reference)
//
#include <hip/hip_runtime.h>
#include <stdint.h>

// Shapes (fixed by the problem)
#define BB 16
#define NN 4096   // 64*64 spatial
#define CC 512    // channels

typedef __attribute__((ext_vector_type(8))) short bf16x8;   // 8 bf16 in 4 VGPRs
typedef __attribute__((ext_vector_type(4))) float f32x4;    // MFMA 16x16 accum

__device__ __forceinline__ unsigned short to_bf16(float f) {
  unsigned int u = __float_as_uint(f);
  u += 0x7fffu + ((u >> 16) & 1u);           // round-to-nearest-even
  return (unsigned short)(u >> 16);
}

// async global->LDS, 16B per lane; LDS dest = wave-uniform base + lane*16
__device__ __forceinline__ void gload_lds16(const void* g, void* l) {
  __builtin_amdgcn_global_load_lds(
      (const __attribute__((address_space(1))) unsigned int*)g,
      (__attribute__((address_space(3))) unsigned int*)l, 16, 0, 0);
}

// ---------------------------------------------------------------------------
// NT-GEMM core: C[128x128] += A[128xK] * B[128xK]^T, both operands row-major
// K-contiguous bf16 with row stride == KT elements. 256 threads = 4 waves,
// each wave owns a 64x64 quadrant (4x4 fragments of 16x16x32 MFMA).
// LDS tiles are [128 rows][64 k] bf16 = 16 KiB each, staged with
// global_load_lds; chunk position XOR-swizzled by (row&7) so the b128
// fragment reads are bank-conflict-free (rule #21: swizzle source AND read).
// ---------------------------------------------------------------------------
template <int KT>
__device__ __forceinline__ void nt_gemm(const unsigned short* __restrict__ aB,
                                        const unsigned short* __restrict__ bB,
                                        f32x4 acc[4][4],
                                        unsigned short* lA, unsigned short* lB) {
  const int tid  = threadIdx.x;
  const int wid  = tid >> 6;
  const int lane = tid & 63;
  const int wr   = (wid >> 1) * 64;   // wave row base within 128
  const int wc   = (wid & 1) * 64;    // wave col base within 128

  const f32x4 zero = {0.f, 0.f, 0.f, 0.f};
#pragma unroll
  for (int i = 0; i < 4; ++i)
#pragma unroll
    for (int j = 0; j < 4; ++j) acc[i][j] = zero;

  const int srow = lane >> 3;                 // 0..7: row within 8-row issue
  const int gsrc = (lane & 7) ^ srow;         // source chunk pre-swizzle

#pragma unroll 1
  for (int k0 = 0; k0 < KT; k0 += 64) {
    // ---- stage: 16 issues x 1KiB per operand, 4 issues/wave/operand ----
#pragma unroll
    for (int i = 0; i < 4; ++i) {
      const int issue = wid * 4 + i;          // 0..15
      const int row   = issue * 8 + srow;     // 0..127
      const size_t go = (size_t)row * KT + k0 + gsrc * 8;
      gload_lds16(aB + go, lA + issue * 512);
      gload_lds16(bB + go, lB + issue * 512);
    }
    __syncthreads();   // compiler drains vmcnt before s_barrier

    // ---- compute: 2 k-subtiles of 32, 16 MFMA each ----
#pragma unroll
    for (int s = 0; s < 2; ++s) {
      bf16x8 af[4], bfr[4];
#pragma unroll
      for (int mf = 0; mf < 4; ++mf) {
        const int row = wr + mf * 16 + (lane & 15);
        const int ch  = (s * 4 + (lane >> 4)) ^ (row & 7);
        af[mf] = *(const bf16x8*)(lA + row * 64 + ch * 8);
      }
#pragma unroll
      for (int nf = 0; nf < 4; ++nf) {
        const int row = wc + nf * 16 + (lane & 15);
        const int ch  = (s * 4 + (lane >> 4)) ^ (row & 7);
        bfr[nf] = *(const bf16x8*)(lB + row * 64 + ch * 8);
      }
#pragma unroll
      for (int mf = 0; mf < 4; ++mf)
#pragma unroll
        for (int nf = 0; nf < 4; ++nf)
          acc[mf][nf] = __builtin_amdgcn_mfma_f32_16x16x32_bf16(
              af[mf], bfr[nf], acc[mf][nf], 0, 0, 0);
    }
    __syncthreads();
  }
}

// ---------------------------------------------------------------------------
// K1: f32 input -> bf16 copy A16[b][n][c] (ws) + transposed AT16[b][c][n]
// (written into d_out scratch, later overwritten by k_out). 64x64 tiles.
// ---------------------------------------------------------------------------
__global__ __launch_bounds__(256) void k_convert(const float* __restrict__ in,
                                                 unsigned short* __restrict__ a16,
                                                 unsigned short* __restrict__ at16) {
  __shared__ unsigned short lt[64][68];       // [c][n] tile, padded rows
  const int b  = blockIdx.y;
  const int tn = blockIdx.x >> 3, tc = blockIdx.x & 7;
  const int n0 = tn * 64, c0 = tc * 64;
  const float* src = in + ((size_t)b * NN + n0) * CC + c0;
  unsigned short* adst = a16 + ((size_t)b * NN + n0) * CC + c0;

#pragma unroll
  for (int i = 0; i < 4; ++i) {
    const int id = i * 256 + threadIdx.x;
    const int n = id >> 4, ch = id & 15;      // 16 chunks of 4 c each
    float4 v = *(const float4*)(src + (size_t)n * CC + ch * 4);
    ushort4 o;
    o.x = to_bf16(v.x); o.y = to_bf16(v.y); o.z = to_bf16(v.z); o.w = to_bf16(v.w);
    *(ushort4*)(adst + (size_t)n * CC + ch * 4) = o;
    lt[ch * 4 + 0][n] = o.x;
    lt[ch * 4 + 1][n] = o.y;
    lt[ch * 4 + 2][n] = o.z;
    lt[ch * 4 + 3][n] = o.w;
  }
  __syncthreads();
  unsigned short* tdst = at16 + ((size_t)b * CC + c0) * NN + n0;
#pragma unroll
  for (int i = 0; i < 4; ++i) {
    const int id = i * 256 + threadIdx.x;
    const int c = id >> 4, ch2 = id & 15;     // 16 chunks of 4 n each
    uint2 w = *(const uint2*)&lt[c][ch2 * 4];
    *(uint2*)(tdst + (size_t)c * NN + ch2 * 4) = w;
  }
}

// ---------------------------------------------------------------------------
// K2: Gram[b][c][d] = sum_n A[n][c]*A[n][d]  via AT x AT (NT), f32 out.
// ---------------------------------------------------------------------------
__global__ __launch_bounds__(256) void k_gram(const unsigned short* __restrict__ at,
                                              float* __restrict__ gram) {
  __shared__ __align__(16) unsigned short lA[128 * 64];
  __shared__ __align__(16) unsigned short lB[128 * 64];
  const int b  = blockIdx.y;
  const int c0 = (blockIdx.x & 3) * 128;
  const int d0 = (blockIdx.x >> 2) * 128;
  const unsigned short* aB = at + ((size_t)b * CC + c0) * NN;
  const unsigned short* bB = at + ((size_t)b * CC + d0) * NN;
  f32x4 acc[4][4];
  nt_gemm<NN>(aB, bB, acc, lA, lB);

  const int lane = threadIdx.x & 63, wid = threadIdx.x >> 6;
  const int wr = (wid >> 1) * 64, wc = (wid & 1) * 64;
  float* gb = gram + (size_t)b * CC * CC;
#pragma unroll
  for (int mf = 0; mf < 4; ++mf)
#pragma unroll
    for (int nf = 0; nf < 4; ++nf)
#pragma unroll
      for (int r = 0; r < 4; ++r) {
        const int row = c0 + wr + mf * 16 + (lane >> 4) * 4 + r;   // c
        const int col = d0 + wc + nf * 16 + (lane & 15);           // d
        gb[(size_t)row * CC + col] = acc[mf][nf][r];
      }
}

// ---------------------------------------------------------------------------
// K3a: per-row max and 1/sum(exp(v-max)) of Gram rows. 1 wave = 1 row.
// ---------------------------------------------------------------------------
__global__ __launch_bounds__(256) void k_rowstats(const float* __restrict__ gram,
                                                  float2* __restrict__ stats) {
  const int wid = threadIdx.x >> 6, lane = threadIdx.x & 63;
  const int row = blockIdx.x * 4 + wid;               // 0..8191
  const float* src = gram + (size_t)row * CC;
  float4 v0 = *(const float4*)(src + lane * 4);
  float4 v1 = *(const float4*)(src + 256 + lane * 4);
  float m = fmaxf(fmaxf(fmaxf(v0.x, v0.y), fmaxf(v0.z, v0.w)),
                  fmaxf(fmaxf(v1.x, v1.y), fmaxf(v1.z, v1.w)));
#pragma unroll
  for (int off = 32; off > 0; off >>= 1) m = fmaxf(m, __shfl_xor(m, off));
  float s = expf(v0.x - m) + expf(v0.y - m) + expf(v0.z - m) + expf(v0.w - m) +
            expf(v1.x - m) + expf(v1.y - m) + expf(v1.z - m) + expf(v1.w - m);
#pragma unroll
  for (int off = 32; off > 0; off >>= 1) s += __shfl_xor(s, off);
  if (lane == 0) stats[row] = make_float2(m, 1.0f / s);
}

// ---------------------------------------------------------------------------
// K3b: ST[b][d][c] = softmax(Gram)[c][d] in bf16 (transposed, coalesced).
// ---------------------------------------------------------------------------
__global__ __launch_bounds__(256) void k_smax_t(const float* __restrict__ gram,
                                                const float2* __restrict__ stats,
                                                unsigned short* __restrict__ st) {
  __shared__ unsigned short lt[64][68];
  const int b  = blockIdx.y;
  const int c0 = (blockIdx.x >> 3) * 64, d0 = (blockIdx.x & 7) * 64;
  const float* gb = gram + ((size_t)b * CC + c0) * CC + d0;
  const float2* sb = stats + (size_t)b * CC + c0;
#pragma unroll
  for (int i = 0; i < 4; ++i) {
    const int id = i * 256 + threadIdx.x;
    const int c = id >> 4, ch = id & 15;
    const float2 stt = sb[c];
    float4 v = *(const float4*)(gb + (size_t)c * CC + ch * 4);
    float vv[4] = {v.x, v.y, v.z, v.w};
#pragma unroll
    for (int j = 0; j < 4; ++j)
      lt[ch * 4 + j][c] = to_bf16(expf(vv[j] - stt.x) * stt.y);
  }
  __syncthreads();
  unsigned short* ob = st + ((size_t)b * CC + d0) * CC + c0;
#pragma unroll
  for (int i = 0; i < 4; ++i) {
    const int id = i * 256 + threadIdx.x;
    const int d = id >> 4, ch2 = id & 15;
    uint2 w = *(const uint2*)&lt[d][ch2 * 4];
    *(uint2*)(ob + (size_t)d * CC + ch2 * 4) = w;
  }
}

// ---------------------------------------------------------------------------
// K5: out[b][n][d] = gamma * sum_c A[n][c]*S[c][d] + x[b][n][d]
//     = NT-GEMM of A16[n][c] x ST[d][c] with fused epilogue.
// ---------------------------------------------------------------------------
__global__ __launch_bounds__(256) void k_out(const unsigned short* __restrict__ a16,
                                             const unsigned short* __restrict__ st,
                                             const float* __restrict__ x,
                                             const float* __restrict__ gammap,
                                             float* __restrict__ outp) {
  __shared__ __align__(16) unsigned short lA[128 * 64];
  __shared__ __align__(16) unsigned short lB[128 * 64];
  const int b  = blockIdx.y;
  const int mt = blockIdx.x >> 2, nt = blockIdx.x & 3;
  const int n0 = mt * 128, d0 = nt * 128;
  const unsigned short* aB = a16 + ((size_t)b * NN + n0) * CC;
  const unsigned short* bB = st + ((size_t)b * CC + d0) * CC;
  f32x4 acc[4][4];
  nt_gemm<CC>(aB, bB, acc, lA, lB);

  const float g = gammap[0];
  const int lane = threadIdx.x & 63, wid = threadIdx.x >> 6;
  const int wr = (wid >> 1) * 64, wc = (wid & 1) * 64;
  const float* xb = x + ((size_t)b * NN + n0) * CC + d0;
  float* ob = outp + ((size_t)b * NN + n0) * CC + d0;
#pragma unroll
  for (int mf = 0; mf < 4; ++mf)
#pragma unroll
    for (int nf = 0; nf < 4; ++nf)
#pragma unroll
      for (int r = 0; r < 4; ++r) {
        const int row = wr + mf * 16 + (lane >> 4) * 4 + r;   // n within 128
        const int col = wc + nf * 16 + (lane & 15);           // d within 128
        const size_t off = (size_t)row * CC + col;
        ob[off] = fmaf(g, acc[mf][nf][r], xb[off]);
      }
}

// ---------------------------------------------------------------------------
// ws layout:  [0,64MiB)  A16 bf16
//             [64,80)    Gram f32
//             [80,88)    ST bf16
//             [88,+64KiB) row stats (float2)
// AT16 (64 MiB) lives in d_out scratch; k_out fully overwrites d_out.
// ---------------------------------------------------------------------------
extern "C" void kernel_launch(void* const* d_in, const int* in_sizes, int n_in,
                              void* d_out, int out_size, void* d_ws, size_t ws_size,
                              hipStream_t stream) {
  const float* in    = (const float*)d_in[0];
  const float* gamma = (const float*)d_in[1];
  float* outp = (float*)d_out;

  unsigned short* a16  = (unsigned short*)d_ws;
  float*          gram = (float*)((char*)d_ws + ((size_t)64 << 20));
  unsigned short* st   = (unsigned short*)((char*)d_ws + ((size_t)80 << 20));
  float2*         stats = (float2*)((char*)d_ws + ((size_t)88 << 20));
  unsigned short* at16 = (unsigned short*)d_out;   // scratch until k_out

  k_convert<<<dim3(512, 16), 256, 0, stream>>>(in, a16, at16);
  k_gram<<<dim3(16, 16), 256, 0, stream>>>(at16, gram);
  k_rowstats<<<dim3(2048), 256, 0, stream>>>(gram, stats);
  k_smax_t<<<dim3(64, 16), 256, 0, stream>>>(gram, stats, st);
  k_out<<<dim3(128, 16), 256, 0, stream>>>(a16, st, in, gamma, outp);
}

// Round 2
// 370.661 us; speedup vs baseline: 1.0884x; 1.0884x over previous
//
#include <hip/hip_runtime.h>
#include <stdint.h>

// Shapes (fixed by the problem)
#define BB 16
#define NN 4096   // 64*64 spatial
#define CC 512    // channels
#define PELEM ((size_t)BB * CC * CC)   // elems per gram split-K partial

typedef __attribute__((ext_vector_type(8))) short bf16x8;   // 8 bf16 in 4 VGPRs
typedef __attribute__((ext_vector_type(4))) float f32x4;    // MFMA 16x16 accum

__device__ __forceinline__ unsigned short to_bf16(float f) {
  unsigned int u = __float_as_uint(f);
  u += 0x7fffu + ((u >> 16) & 1u);           // round-to-nearest-even
  return (unsigned short)(u >> 16);
}
__device__ __forceinline__ float bf16_to_f32(unsigned short h) {
  return __uint_as_float(((unsigned int)h) << 16);
}

// async global->LDS, 16B per lane; LDS dest = wave-uniform base + lane*16
__device__ __forceinline__ void gload_lds16(const void* g, void* l) {
  __builtin_amdgcn_global_load_lds(
      (const __attribute__((address_space(1))) unsigned int*)g,
      (__attribute__((address_space(3))) unsigned int*)l, 16, 0, 0);
}

// ---------------------------------------------------------------------------
// NT-GEMM core: C[128x128] += A[128xKLEN] * B[128xKLEN]^T, operands row-major
// K-contiguous bf16, row stride RS elements. 256 threads = 4 waves, each wave
// a 64x64 quadrant (4x4 frags of 16x16x32 MFMA). LDS tiles [128][64] bf16,
// staged via global_load_lds with XOR source-pre-swizzle by (row&7) so the
// b128 fragment reads are bank-conflict-free (both-sides-or-neither).
// ---------------------------------------------------------------------------
template <int RS, int KLEN>
__device__ __forceinline__ void nt_gemm(const unsigned short* __restrict__ aB,
                                        const unsigned short* __restrict__ bB,
                                        f32x4 acc[4][4],
                                        unsigned short* lA, unsigned short* lB) {
  const int tid  = threadIdx.x;
  const int wid  = tid >> 6;
  const int lane = tid & 63;
  const int wr   = (wid >> 1) * 64;   // wave row base within 128
  const int wc   = (wid & 1) * 64;    // wave col base within 128

  const f32x4 zero = {0.f, 0.f, 0.f, 0.f};
#pragma unroll
  for (int i = 0; i < 4; ++i)
#pragma unroll
    for (int j = 0; j < 4; ++j) acc[i][j] = zero;

  const int srow = lane >> 3;                 // 0..7: row within 8-row issue
  const int gsrc = (lane & 7) ^ srow;         // source chunk pre-swizzle

#pragma unroll 1
  for (int k0 = 0; k0 < KLEN; k0 += 64) {
    // ---- stage: 16 issues x 1KiB per operand, 4 issues/wave/operand ----
#pragma unroll
    for (int i = 0; i < 4; ++i) {
      const int issue = wid * 4 + i;          // 0..15
      const int row   = issue * 8 + srow;     // 0..127
      const size_t go = (size_t)row * RS + k0 + gsrc * 8;
      gload_lds16(aB + go, lA + issue * 512);
      gload_lds16(bB + go, lB + issue * 512);
    }
    __syncthreads();   // compiler drains vmcnt before s_barrier

    // ---- compute: 2 k-subtiles of 32, 16 MFMA each ----
#pragma unroll
    for (int s = 0; s < 2; ++s) {
      bf16x8 af[4], bfr[4];
#pragma unroll
      for (int mf = 0; mf < 4; ++mf) {
        const int row = wr + mf * 16 + (lane & 15);
        const int ch  = (s * 4 + (lane >> 4)) ^ (row & 7);
        af[mf] = *(const bf16x8*)(lA + row * 64 + ch * 8);
      }
#pragma unroll
      for (int nf = 0; nf < 4; ++nf) {
        const int row = wc + nf * 16 + (lane & 15);
        const int ch  = (s * 4 + (lane >> 4)) ^ (row & 7);
        bfr[nf] = *(const bf16x8*)(lB + row * 64 + ch * 8);
      }
#pragma unroll
      for (int mf = 0; mf < 4; ++mf)
#pragma unroll
        for (int nf = 0; nf < 4; ++nf)
          acc[mf][nf] = __builtin_amdgcn_mfma_f32_16x16x32_bf16(
              af[mf], bfr[nf], acc[mf][nf], 0, 0, 0);
    }
    __syncthreads();
  }
}

// ---------------------------------------------------------------------------
// K1: f32 input -> bf16 copy A16[b][n][c] (ws) + transposed AT16[b][c][n]
// (written into d_out[0,64MiB) scratch; k_out overwrites d_out at the end).
// ---------------------------------------------------------------------------
__global__ __launch_bounds__(256) void k_convert(const float* __restrict__ in,
                                                 unsigned short* __restrict__ a16,
                                                 unsigned short* __restrict__ at16) {
  __shared__ unsigned short lt[64][68];       // [c][n] tile, padded rows
  const int b  = blockIdx.y;
  const int tn = blockIdx.x >> 3, tc = blockIdx.x & 7;
  const int n0 = tn * 64, c0 = tc * 64;
  const float* src = in + ((size_t)b * NN + n0) * CC + c0;
  unsigned short* adst = a16 + ((size_t)b * NN + n0) * CC + c0;

#pragma unroll
  for (int i = 0; i < 4; ++i) {
    const int id = i * 256 + threadIdx.x;
    const int n = id >> 4, ch = id & 15;      // 16 chunks of 4 c each
    float4 v = *(const float4*)(src + (size_t)n * CC + ch * 4);
    ushort4 o;
    o.x = to_bf16(v.x); o.y = to_bf16(v.y); o.z = to_bf16(v.z); o.w = to_bf16(v.w);
    *(ushort4*)(adst + (size_t)n * CC + ch * 4) = o;
    lt[ch * 4 + 0][n] = o.x;
    lt[ch * 4 + 1][n] = o.y;
    lt[ch * 4 + 2][n] = o.z;
    lt[ch * 4 + 3][n] = o.w;
  }
  __syncthreads();
  unsigned short* tdst = at16 + ((size_t)b * CC + c0) * NN + n0;
#pragma unroll
  for (int i = 0; i < 4; ++i) {
    const int id = i * 256 + threadIdx.x;
    const int c = id >> 4, ch2 = id & 15;     // 16 chunks of 4 n each
    uint2 w = *(const uint2*)&lt[c][ch2 * 4];
    *(uint2*)(tdst + (size_t)c * NN + ch2 * 4) = w;
  }
}

// ---------------------------------------------------------------------------
// K2: split-K Gram partials. parts[ks][b][c][d] = sum_{n in ks-range} A^T A.
// 1024 blocks; XCD-chunked swizzle: each XCD runs 2 batches, ks-major order
// so concurrent blocks share a 1 MiB k-panel in their XCD's L2.
// ---------------------------------------------------------------------------
__global__ __launch_bounds__(256) void k_gram(const unsigned short* __restrict__ at,
                                              float* __restrict__ parts) {
  __shared__ __align__(16) unsigned short lA[128 * 64];
  __shared__ __align__(16) unsigned short lB[128 * 64];
  const int bid  = blockIdx.x;
  const int work = (bid & 7) * 128 + (bid >> 3);   // chunked XCD swizzle (1024%8==0)
  const int b    = work >> 6;                       // 64 works per batch
  const int r    = work & 63;
  const int ks   = r >> 4;                          // k-split 0..3 (outer)
  const int tile = r & 15;                          // 4x4 tile grid
  const int c0 = (tile & 3) * 128;
  const int d0 = (tile >> 2) * 128;
  const unsigned short* aB = at + ((size_t)b * CC + c0) * NN + ks * 1024;
  const unsigned short* bB = at + ((size_t)b * CC + d0) * NN + ks * 1024;
  f32x4 acc[4][4];
  nt_gemm<NN, 1024>(aB, bB, acc, lA, lB);

  const int lane = threadIdx.x & 63, wid = threadIdx.x >> 6;
  const int wr = (wid >> 1) * 64, wc = (wid & 1) * 64;
  float* gb = parts + (size_t)ks * PELEM + (size_t)b * CC * CC;
#pragma unroll
  for (int mf = 0; mf < 4; ++mf)
#pragma unroll
    for (int nf = 0; nf < 4; ++nf)
#pragma unroll
      for (int q = 0; q < 4; ++q) {
        const int row = c0 + wr + mf * 16 + (lane >> 4) * 4 + q;   // c
        const int col = d0 + wc + nf * 16 + (lane & 15);           // d
        gb[(size_t)row * CC + col] = acc[mf][nf][q];
      }
}

// ---------------------------------------------------------------------------
// K3: fused: sum 4 partials -> row max -> exp/sum -> bf16 softmax -> ST[d][c]
// (transposed write via XOR-swizzled LDS). 1 wave = 1 row at a time.
// ---------------------------------------------------------------------------
__global__ __launch_bounds__(256) void k_softmax(const float* __restrict__ parts,
                                                 unsigned short* __restrict__ st) {
  __shared__ unsigned short ls[32][512];      // [c-local][d], XOR-swizzled groups
  const int b  = blockIdx.x >> 4;
  const int cb = blockIdx.x & 15;             // 16 c-blocks of 32 rows
  const int wid = threadIdx.x >> 6, lane = threadIdx.x & 63;

#pragma unroll 1
  for (int i = 0; i < 8; ++i) {
    const int rl = wid * 8 + i;               // 0..31
    const int c  = cb * 32 + rl;
    const int r7 = rl & 7;
    const float* base = parts + ((size_t)b * CC + c) * CC;
    float4 v0 = {0.f, 0.f, 0.f, 0.f}, v1 = {0.f, 0.f, 0.f, 0.f};
#pragma unroll
    for (int p = 0; p < 4; ++p) {
      float4 a = *(const float4*)(base + (size_t)p * PELEM + lane * 4);
      float4 bq = *(const float4*)(base + (size_t)p * PELEM + 256 + lane * 4);
      v0.x += a.x; v0.y += a.y; v0.z += a.z; v0.w += a.w;
      v1.x += bq.x; v1.y += bq.y; v1.z += bq.z; v1.w += bq.w;
    }
    float m = fmaxf(fmaxf(fmaxf(v0.x, v0.y), fmaxf(v0.z, v0.w)),
                    fmaxf(fmaxf(v1.x, v1.y), fmaxf(v1.z, v1.w)));
#pragma unroll
    for (int off = 32; off > 0; off >>= 1) m = fmaxf(m, __shfl_xor(m, off));
    float e0 = expf(v0.x - m), e1 = expf(v0.y - m), e2 = expf(v0.z - m), e3 = expf(v0.w - m);
    float e4 = expf(v1.x - m), e5 = expf(v1.y - m), e6 = expf(v1.z - m), e7 = expf(v1.w - m);
    float s = e0 + e1 + e2 + e3 + e4 + e5 + e6 + e7;
#pragma unroll
    for (int off = 32; off > 0; off >>= 1) s += __shfl_xor(s, off);
    const float pinv = 1.0f / s;
    ushort4 o0, o1;
    o0.x = to_bf16(e0 * pinv); o0.y = to_bf16(e1 * pinv);
    o0.z = to_bf16(e2 * pinv); o0.w = to_bf16(e3 * pinv);
    o1.x = to_bf16(e4 * pinv); o1.y = to_bf16(e5 * pinv);
    o1.z = to_bf16(e6 * pinv); o1.w = to_bf16(e7 * pinv);
    *(ushort4*)&ls[rl][(lane ^ r7) << 2]         = o0;   // d-group XOR swizzle
    *(ushort4*)&ls[rl][256 + ((lane ^ r7) << 2)] = o1;
  }
  __syncthreads();

  // transposed write: thread t handles d = t and d = 256+t; 32 c's each
#pragma unroll 1
  for (int i = 0; i < 2; ++i) {
    const int d = i * 256 + threadIdx.x;
    unsigned int u[16];
#pragma unroll
    for (int k = 0; k < 16; ++k) {
      const int c0i = 2 * k, c1i = 2 * k + 1;
      const unsigned int lo = ls[c0i][(((d >> 2) ^ (c0i & 7)) << 2) | (d & 3)];
      const unsigned int hi = ls[c1i][(((d >> 2) ^ (c1i & 7)) << 2) | (d & 3)];
      u[k] = lo | (hi << 16);
    }
    unsigned short* dst = st + ((size_t)b * CC + d) * CC + cb * 32;
    uint4 w0 = {u[0], u[1], u[2], u[3]};
    uint4 w1 = {u[4], u[5], u[6], u[7]};
    uint4 w2 = {u[8], u[9], u[10], u[11]};
    uint4 w3 = {u[12], u[13], u[14], u[15]};
    *(uint4*)(dst + 0)  = w0;
    *(uint4*)(dst + 8)  = w1;
    *(uint4*)(dst + 16) = w2;
    *(uint4*)(dst + 24) = w3;
  }
}

// ---------------------------------------------------------------------------
// K4: out[b][n][d] = gamma * sum_c A[n][c]*S[c][d] + x[b][n][d]
//     NT-GEMM A16[n][c] x ST[d][c]; residual read from a16 (bf16, L2-hot)
//     instead of f32 x -> saves 128 MB of HBM fetch per launch.
// ---------------------------------------------------------------------------
__global__ __launch_bounds__(256) void k_out(const unsigned short* __restrict__ a16,
                                             const unsigned short* __restrict__ st,
                                             const float* __restrict__ gammap,
                                             float* __restrict__ outp) {
  __shared__ __align__(16) unsigned short lA[128 * 64];
  __shared__ __align__(16) unsigned short lB[128 * 64];
  const int bid  = blockIdx.x;
  const int work = (bid & 7) * 256 + (bid >> 3);   // chunked XCD swizzle (2048%8==0)
  const int b    = work >> 7;                       // 128 works per batch
  const int r    = work & 127;
  const int nt   = r >> 5;                          // nt-major: st panel L2-hot
  const int mt   = r & 31;
  const int n0 = mt * 128, d0 = nt * 128;
  const unsigned short* aB = a16 + ((size_t)b * NN + n0) * CC;
  const unsigned short* bB = st + ((size_t)b * CC + d0) * CC;
  f32x4 acc[4][4];
  nt_gemm<CC, CC>(aB, bB, acc, lA, lB);

  const float g = gammap[0];
  const int lane = threadIdx.x & 63, wid = threadIdx.x >> 6;
  const int wr = (wid >> 1) * 64, wc = (wid & 1) * 64;
  const unsigned short* xr = a16 + ((size_t)b * NN + n0) * CC + d0;
  float* ob = outp + ((size_t)b * NN + n0) * CC + d0;
#pragma unroll
  for (int mf = 0; mf < 4; ++mf)
#pragma unroll
    for (int nf = 0; nf < 4; ++nf)
#pragma unroll
      for (int q = 0; q < 4; ++q) {
        const int row = wr + mf * 16 + (lane >> 4) * 4 + q;   // n within 128
        const int col = wc + nf * 16 + (lane & 15);           // d within 128
        const size_t off = (size_t)row * CC + col;
        ob[off] = fmaf(g, acc[mf][nf][q], bf16_to_f32(xr[off]));
      }
}

// ---------------------------------------------------------------------------
// Memory plan:
//   ws   [0,64MiB)   A16 bf16            (64 MiB)
//        [64,72MiB)  ST bf16             (8 MiB)     -> ws need: 72 MiB
//   d_out[0,64MiB)   AT16 bf16 scratch   (k_convert -> k_gram)
//        [64,128MiB) gram partials f32 x4 (k_gram -> k_softmax)
//   k_out fully overwrites d_out with the final 128 MiB output.
// ---------------------------------------------------------------------------
extern "C" void kernel_launch(void* const* d_in, const int* in_sizes, int n_in,
                              void* d_out, int out_size, void* d_ws, size_t ws_size,
                              hipStream_t stream) {
  const float* in    = (const float*)d_in[0];
  const float* gamma = (const float*)d_in[1];
  float* outp = (float*)d_out;

  unsigned short* a16  = (unsigned short*)d_ws;
  unsigned short* stb  = (unsigned short*)((char*)d_ws + ((size_t)64 << 20));
  unsigned short* at16 = (unsigned short*)d_out;                      // [0,64MiB)
  float*          parts = (float*)((char*)d_out + ((size_t)64 << 20)); // [64,128MiB)

  k_convert<<<dim3(512, 16), 256, 0, stream>>>(in, a16, at16);
  k_gram<<<dim3(1024), 256, 0, stream>>>(at16, parts);
  k_softmax<<<dim3(256), 256, 0, stream>>>(parts, stb);
  k_out<<<dim3(2048), 256, 0, stream>>>(a16, stb, gamma, outp);
}

// Round 3
// 356.704 us; speedup vs baseline: 1.1310x; 1.0391x over previous
//
#include <hip/hip_runtime.h>
#include <stdint.h>

// Shapes (fixed by the problem)
#define BB 16
#define NN 4096   // 64*64 spatial
#define CC 512    // channels
#define PELEM ((size_t)BB * CC * CC)   // elems per gram split-K partial

typedef __attribute__((ext_vector_type(8))) short bf16x8;   // 8 bf16 in 4 VGPRs
typedef __attribute__((ext_vector_type(4))) float f32x4;    // MFMA 16x16 accum

__device__ __forceinline__ unsigned short to_bf16(float f) {
  unsigned int u = __float_as_uint(f);
  u += 0x7fffu + ((u >> 16) & 1u);           // round-to-nearest-even
  return (unsigned short)(u >> 16);
}
__device__ __forceinline__ float bf16_to_f32(unsigned short h) {
  return __uint_as_float(((unsigned int)h) << 16);
}

// async global->LDS, 16B per lane; LDS dest = wave-uniform base + lane*16
__device__ __forceinline__ void gload_lds16(const void* g, void* l) {
  __builtin_amdgcn_global_load_lds(
      (const __attribute__((address_space(1))) unsigned int*)g,
      (__attribute__((address_space(3))) unsigned int*)l, 16, 0, 0);
}

// ---------------------------------------------------------------------------
// NT-GEMM core, double-buffered (T3 minimum-2-phase): issue next tile's
// global_load_lds BEFORE compute on current tile; the __syncthreads() at the
// end of the iteration drains vmcnt AFTER the MFMA phase, so staging latency
// hides under compute. LDS layout: [buf][A 8192 | B 8192] ushorts (64 KiB).
// C[128x128] += A[128xKLEN] * B[128xKLEN]^T, row-major K-contiguous bf16,
// row stride RS. 256 thr = 4 waves, each a 64x64 quadrant (4x4 frags of
// 16x16x32 MFMA). XOR source-pre-swizzle by (row&7) on the staged chunks so
// the b128 fragment reads are bank-conflict-free (both-sides-or-neither).
// ---------------------------------------------------------------------------
template <int RS, int KLEN>
__device__ __forceinline__ void nt_gemm(const unsigned short* __restrict__ aB,
                                        const unsigned short* __restrict__ bB,
                                        f32x4 acc[4][4],
                                        unsigned short* lds) {
  const int tid  = threadIdx.x;
  const int wid  = tid >> 6;
  const int lane = tid & 63;
  const int wr   = (wid >> 1) * 64;   // wave row base within 128
  const int wc   = (wid & 1) * 64;    // wave col base within 128

  const f32x4 zero = {0.f, 0.f, 0.f, 0.f};
#pragma unroll
  for (int i = 0; i < 4; ++i)
#pragma unroll
    for (int j = 0; j < 4; ++j) acc[i][j] = zero;

  const int srow = lane >> 3;                 // 0..7: row within 8-row issue
  const int gsrc = (lane & 7) ^ srow;         // source chunk pre-swizzle
  constexpr int NT = KLEN / 64;

  auto stage = [&](int bf, int k0) {
#pragma unroll
    for (int i = 0; i < 4; ++i) {
      const int issue = wid * 4 + i;          // 0..15
      const int row   = issue * 8 + srow;     // 0..127
      const size_t go = (size_t)row * RS + k0 + gsrc * 8;
      gload_lds16(aB + go, lds + bf * 16384 + issue * 512);
      gload_lds16(bB + go, lds + bf * 16384 + 8192 + issue * 512);
    }
  };
  auto compute = [&](int bf) {
    const unsigned short* lA = lds + bf * 16384;
    const unsigned short* lB = lA + 8192;
#pragma unroll
    for (int s = 0; s < 2; ++s) {
      bf16x8 af[4], bfr[4];
#pragma unroll
      for (int mf = 0; mf < 4; ++mf) {
        const int row = wr + mf * 16 + (lane & 15);
        const int ch  = (s * 4 + (lane >> 4)) ^ (row & 7);
        af[mf] = *(const bf16x8*)(lA + row * 64 + ch * 8);
      }
#pragma unroll
      for (int nf = 0; nf < 4; ++nf) {
        const int row = wc + nf * 16 + (lane & 15);
        const int ch  = (s * 4 + (lane >> 4)) ^ (row & 7);
        bfr[nf] = *(const bf16x8*)(lB + row * 64 + ch * 8);
      }
#pragma unroll
      for (int mf = 0; mf < 4; ++mf)
#pragma unroll
        for (int nf = 0; nf < 4; ++nf)
          acc[mf][nf] = __builtin_amdgcn_mfma_f32_16x16x32_bf16(
              af[mf], bfr[nf], acc[mf][nf], 0, 0, 0);
    }
  };

  stage(0, 0);
  __syncthreads();                 // prologue drain
  int cur = 0;
#pragma unroll 1
  for (int t = 0; t < NT; ++t) {
    if (t + 1 < NT) stage(cur ^ 1, (t + 1) * 64);   // prefetch next tile
    compute(cur);                                    // MFMA on current
    __syncthreads();               // drains prefetch vmcnt after compute
    cur ^= 1;
  }
}

// ---------------------------------------------------------------------------
// K1: f32 input -> bf16 A16[b][n][c] (ws) + transposed AT16[b][c][n] (d_out
// scratch). 64x64 tiles; each thread transposes a 4x4 micro-tile in regs.
// All LDS traffic is b64 at the 512B/wave floor (stride-68 rows -> exactly
// 4 lanes per bank-pair, conflict-free); global stores in >=64B segments.
// ---------------------------------------------------------------------------
__global__ __launch_bounds__(256) void k_convert(const float* __restrict__ in,
                                                 unsigned short* __restrict__ a16,
                                                 unsigned short* __restrict__ at16) {
  __shared__ unsigned short lt[64 * 68];      // [c][n], row stride 68 ushorts
  const int b  = blockIdx.y;
  const int tn = blockIdx.x >> 3, tc = blockIdx.x & 7;
  const int n0 = tn * 64, c0 = tc * 64;
  const int t   = threadIdx.x;
  const int ctc = t & 15;                     // c-quad index (0..15)
  const int ntq = t >> 4;                     // n-quad index (0..15)

  const float* src = in + ((size_t)b * NN + n0 + 4 * ntq) * CC + c0 + 4 * ctc;
  unsigned short* adst = a16 + ((size_t)b * NN + n0 + 4 * ntq) * CC + c0 + 4 * ctc;

  unsigned short ob[4][4];                    // [n-local][c-local]
#pragma unroll
  for (int j = 0; j < 4; ++j) {
    float4 v = *(const float4*)(src + (size_t)j * CC);
    ob[j][0] = to_bf16(v.x); ob[j][1] = to_bf16(v.y);
    ob[j][2] = to_bf16(v.z); ob[j][3] = to_bf16(v.w);
    ushort4 o = {ob[j][0], ob[j][1], ob[j][2], ob[j][3]};
    *(ushort4*)(adst + (size_t)j * CC) = o;   // 128B contiguous per 16 lanes
  }
  // transposed LDS write: row c = 4*ctc+q, n-chunk ntq (b64, conflict-free)
#pragma unroll
  for (int q = 0; q < 4; ++q) {
    ushort4 w = {ob[0][q], ob[1][q], ob[2][q], ob[3][q]};
    *(ushort4*)&lt[(4 * ctc + q) * 68 + 4 * ntq] = w;
  }
  __syncthreads();

  // at16 write: thread t -> c row t>>2, n-chunks 8*(t&3)+{0..7} and +32
  const int c_l = t >> 2, w4 = t & 3;
  const unsigned short* lr = lt + c_l * 68;
  uint2 r0a = *(const uint2*)(lr + 8 * w4);
  uint2 r0b = *(const uint2*)(lr + 8 * w4 + 4);
  uint2 r1a = *(const uint2*)(lr + 8 * w4 + 32);
  uint2 r1b = *(const uint2*)(lr + 8 * w4 + 36);
  unsigned short* tb = at16 + ((size_t)b * CC + c0 + c_l) * NN + n0;
  uint4 s0 = {r0a.x, r0a.y, r0b.x, r0b.y};
  uint4 s1 = {r1a.x, r1a.y, r1b.x, r1b.y};
  *(uint4*)(tb + 8 * w4)      = s0;           // 64B contiguous per 4 lanes
  *(uint4*)(tb + 8 * w4 + 32) = s1;
}

// ---------------------------------------------------------------------------
// K2: split-K Gram partials, SYMMETRIC: only 10 upper-triangle 128^2 tiles
// (of 16); off-diagonal tiles also write the mirrored tile via an LDS
// transpose (stride-132 f32: conflict-free). parts[ks][b][c][d].
// Grid 640 = 16 b x 10 tiles x 4 ks; ks-outer XCD swizzle keeps each 1 MiB
// k-panel L2-resident.
// ---------------------------------------------------------------------------
__global__ __launch_bounds__(256) void k_gram(const unsigned short* __restrict__ at,
                                              float* __restrict__ parts) {
  __shared__ __align__(16) unsigned short lds[32768];   // 64 KiB
  const int bid  = blockIdx.x;
  const int work = (bid & 7) * 80 + (bid >> 3);   // chunked XCD swizzle (640%8==0)
  const int b    = work / 40;
  const int r    = work % 40;
  const int ks   = r / 10;                         // ks-outer within batch group
  const int t10  = r % 10;                         // triangle tile id
  const int ti = t10 < 4 ? 0 : t10 < 7 ? 1 : t10 < 9 ? 2 : 3;
  const int tj = t10 < 4 ? t10 : t10 < 7 ? t10 - 3 : t10 < 9 ? t10 - 5 : 3;
  const int c0 = ti * 128, d0 = tj * 128;

  const unsigned short* aB = at + ((size_t)b * CC + c0) * NN + ks * 1024;
  const unsigned short* bB = at + ((size_t)b * CC + d0) * NN + ks * 1024;
  f32x4 acc[4][4];
  nt_gemm<NN, 1024>(aB, bB, acc, lds);

  const int tid = threadIdx.x;
  const int lane = tid & 63, wid = tid >> 6;
  const int wr = (wid >> 1) * 64, wc = (wid & 1) * 64;
  float* gb = parts + (size_t)ks * PELEM + (size_t)b * CC * CC;

  // normal tile write (c rows, d cols) — coalesced
#pragma unroll
  for (int mf = 0; mf < 4; ++mf)
#pragma unroll
    for (int nf = 0; nf < 4; ++nf)
#pragma unroll
      for (int q = 0; q < 4; ++q) {
        const int row = c0 + wr + mf * 16 + (lane >> 4) * 4 + q;   // c
        const int col = d0 + wc + nf * 16 + (lane & 15);           // d
        gb[(size_t)row * CC + col] = acc[mf][nf][q];
      }

  if (c0 != d0) {
    // mirrored tile via LDS transpose, two 64-row halves
    float* sf = (float*)lds;                  // 64 x 132 f32 = 33.8 KiB
#pragma unroll 1
    for (int h = 0; h < 2; ++h) {
      __syncthreads();
      if ((wid >> 1) == h) {                  // waves owning rows 64h..64h+63
#pragma unroll
        for (int mf = 0; mf < 4; ++mf)
#pragma unroll
          for (int nf = 0; nf < 4; ++nf)
#pragma unroll
            for (int q = 0; q < 4; ++q) {
              const int row_l = mf * 16 + (lane >> 4) * 4 + q;     // 0..63
              const int col   = wc + nf * 16 + (lane & 15);        // 0..127
              sf[row_l * 132 + col] = acc[mf][nf][q];
            }
      }
      __syncthreads();
      const int d_l = tid >> 1;               // 0..127 (col of orig tile)
      const int rh  = tid & 1;                // 32-row half
      float vals[32];
#pragma unroll
      for (int u = 0; u < 32; ++u) vals[u] = sf[(32 * rh + u) * 132 + d_l];
      float* dst = gb + (size_t)(d0 + d_l) * CC + c0 + 64 * h + 32 * rh;
#pragma unroll
      for (int s = 0; s < 8; ++s) {
        float4 w = {vals[4 * s], vals[4 * s + 1], vals[4 * s + 2], vals[4 * s + 3]};
        *(float4*)(dst + 4 * s) = w;
      }
    }
  }
}

// ---------------------------------------------------------------------------
// K3: fused: sum 4 partials -> row max -> exp/sum -> bf16 softmax -> ST[d][c]
// (transposed write via XOR-swizzled LDS). 1 wave = 1 row at a time.
// ---------------------------------------------------------------------------
__global__ __launch_bounds__(256) void k_softmax(const float* __restrict__ parts,
                                                 unsigned short* __restrict__ st) {
  __shared__ unsigned short ls[32][512];      // [c-local][d], XOR-swizzled groups
  const int b  = blockIdx.x >> 4;
  const int cb = blockIdx.x & 15;             // 16 c-blocks of 32 rows
  const int wid = threadIdx.x >> 6, lane = threadIdx.x & 63;

#pragma unroll 1
  for (int i = 0; i < 8; ++i) {
    const int rl = wid * 8 + i;               // 0..31
    const int c  = cb * 32 + rl;
    const int r7 = rl & 7;
    const float* base = parts + ((size_t)b * CC + c) * CC;
    float4 v0 = {0.f, 0.f, 0.f, 0.f}, v1 = {0.f, 0.f, 0.f, 0.f};
#pragma unroll
    for (int p = 0; p < 4; ++p) {
      float4 a = *(const float4*)(base + (size_t)p * PELEM + lane * 4);
      float4 bq = *(const float4*)(base + (size_t)p * PELEM + 256 + lane * 4);
      v0.x += a.x; v0.y += a.y; v0.z += a.z; v0.w += a.w;
      v1.x += bq.x; v1.y += bq.y; v1.z += bq.z; v1.w += bq.w;
    }
    float m = fmaxf(fmaxf(fmaxf(v0.x, v0.y), fmaxf(v0.z, v0.w)),
                    fmaxf(fmaxf(v1.x, v1.y), fmaxf(v1.z, v1.w)));
#pragma unroll
    for (int off = 32; off > 0; off >>= 1) m = fmaxf(m, __shfl_xor(m, off));
    float e0 = expf(v0.x - m), e1 = expf(v0.y - m), e2 = expf(v0.z - m), e3 = expf(v0.w - m);
    float e4 = expf(v1.x - m), e5 = expf(v1.y - m), e6 = expf(v1.z - m), e7 = expf(v1.w - m);
    float s = e0 + e1 + e2 + e3 + e4 + e5 + e6 + e7;
#pragma unroll
    for (int off = 32; off > 0; off >>= 1) s += __shfl_xor(s, off);
    const float pinv = 1.0f / s;
    ushort4 o0, o1;
    o0.x = to_bf16(e0 * pinv); o0.y = to_bf16(e1 * pinv);
    o0.z = to_bf16(e2 * pinv); o0.w = to_bf16(e3 * pinv);
    o1.x = to_bf16(e4 * pinv); o1.y = to_bf16(e5 * pinv);
    o1.z = to_bf16(e6 * pinv); o1.w = to_bf16(e7 * pinv);
    *(ushort4*)&ls[rl][(lane ^ r7) << 2]         = o0;   // d-group XOR swizzle
    *(ushort4*)&ls[rl][256 + ((lane ^ r7) << 2)] = o1;
  }
  __syncthreads();

  // transposed write: thread t handles d = t and d = 256+t; 32 c's each
#pragma unroll 1
  for (int i = 0; i < 2; ++i) {
    const int d = i * 256 + threadIdx.x;
    unsigned int u[16];
#pragma unroll
    for (int k = 0; k < 16; ++k) {
      const int c0i = 2 * k, c1i = 2 * k + 1;
      const unsigned int lo = ls[c0i][(((d >> 2) ^ (c0i & 7)) << 2) | (d & 3)];
      const unsigned int hi = ls[c1i][(((d >> 2) ^ (c1i & 7)) << 2) | (d & 3)];
      u[k] = lo | (hi << 16);
    }
    unsigned short* dst = st + ((size_t)b * CC + d) * CC + cb * 32;
    uint4 w0 = {u[0], u[1], u[2], u[3]};
    uint4 w1 = {u[4], u[5], u[6], u[7]};
    uint4 w2 = {u[8], u[9], u[10], u[11]};
    uint4 w3 = {u[12], u[13], u[14], u[15]};
    *(uint4*)(dst + 0)  = w0;
    *(uint4*)(dst + 8)  = w1;
    *(uint4*)(dst + 16) = w2;
    *(uint4*)(dst + 24) = w3;
  }
}

// ---------------------------------------------------------------------------
// K4: out[b][n][d] = gamma * sum_c A[n][c]*S[c][d] + x[b][n][d]
//     NT-GEMM A16[n][c] x ST[d][c]; residual read from a16 (bf16, L2-hot).
// ---------------------------------------------------------------------------
__global__ __launch_bounds__(256) void k_out(const unsigned short* __restrict__ a16,
                                             const unsigned short* __restrict__ st,
                                             const float* __restrict__ gammap,
                                             float* __restrict__ outp) {
  __shared__ __align__(16) unsigned short lds[32768];   // 64 KiB dbuf
  const int bid  = blockIdx.x;
  const int work = (bid & 7) * 256 + (bid >> 3);   // chunked XCD swizzle (2048%8==0)
  const int b    = work >> 7;                       // 128 works per batch
  const int r    = work & 127;
  const int nt   = r >> 5;                          // nt-major: st panel L2-hot
  const int mt   = r & 31;
  const int n0 = mt * 128, d0 = nt * 128;
  const unsigned short* aB = a16 + ((size_t)b * NN + n0) * CC;
  const unsigned short* bB = st + ((size_t)b * CC + d0) * CC;
  f32x4 acc[4][4];
  nt_gemm<CC, CC>(aB, bB, acc, lds);

  const float g = gammap[0];
  const int lane = threadIdx.x & 63, wid = threadIdx.x >> 6;
  const int wr = (wid >> 1) * 64, wc = (wid & 1) * 64;
  const unsigned short* xr = a16 + ((size_t)b * NN + n0) * CC + d0;
  float* ob = outp + ((size_t)b * NN + n0) * CC + d0;
#pragma unroll
  for (int mf = 0; mf < 4; ++mf)
#pragma unroll
    for (int nf = 0; nf < 4; ++nf)
#pragma unroll
      for (int q = 0; q < 4; ++q) {
        const int row = wr + mf * 16 + (lane >> 4) * 4 + q;   // n within 128
        const int col = wc + nf * 16 + (lane & 15);           // d within 128
        const size_t off = (size_t)row * CC + col;
        ob[off] = fmaf(g, acc[mf][nf][q], bf16_to_f32(xr[off]));
      }
}

// ---------------------------------------------------------------------------
// Memory plan:
//   ws   [0,64MiB)   A16 bf16            (64 MiB)
//        [64,72MiB)  ST bf16             (8 MiB)     -> ws need: 72 MiB
//   d_out[0,64MiB)   AT16 bf16 scratch   (k_convert -> k_gram)
//        [64,128MiB) gram partials f32x4 (k_gram -> k_softmax)
//   k_out fully overwrites d_out with the final 128 MiB output.
// ---------------------------------------------------------------------------
extern "C" void kernel_launch(void* const* d_in, const int* in_sizes, int n_in,
                              void* d_out, int out_size, void* d_ws, size_t ws_size,
                              hipStream_t stream) {
  const float* in    = (const float*)d_in[0];
  const float* gamma = (const float*)d_in[1];
  float* outp = (float*)d_out;

  unsigned short* a16  = (unsigned short*)d_ws;
  unsigned short* stb  = (unsigned short*)((char*)d_ws + ((size_t)64 << 20));
  unsigned short* at16 = (unsigned short*)d_out;                      // [0,64MiB)
  float*          parts = (float*)((char*)d_out + ((size_t)64 << 20)); // [64,128MiB)

  k_convert<<<dim3(512, 16), 256, 0, stream>>>(in, a16, at16);
  k_gram<<<dim3(640), 256, 0, stream>>>(at16, parts);
  k_softmax<<<dim3(256), 256, 0, stream>>>(parts, stb);
  k_out<<<dim3(2048), 256, 0, stream>>>(a16, stb, gamma, outp);
}

// Round 4
// 352.645 us; speedup vs baseline: 1.1440x; 1.0115x over previous
//
#include <hip/hip_runtime.h>
#include <stdint.h>

// Shapes (fixed by the problem)
#define BB 16
#define NN 4096   // 64*64 spatial
#define CC 512    // channels
#define PELEM ((size_t)BB * CC * CC)   // elems per gram split-K partial

typedef __attribute__((ext_vector_type(8))) short bf16x8;   // 8 bf16 in 4 VGPRs
typedef __attribute__((ext_vector_type(4))) float f32x4;    // MFMA 16x16 accum

__device__ __forceinline__ unsigned short to_bf16(float f) {
  unsigned int u = __float_as_uint(f);
  u += 0x7fffu + ((u >> 16) & 1u);           // round-to-nearest-even
  return (unsigned short)(u >> 16);
}
__device__ __forceinline__ float bf16_to_f32(unsigned short h) {
  return __uint_as_float(((unsigned int)h) << 16);
}

// async global->LDS, 16B per lane; LDS dest = wave-uniform base + lane*16
__device__ __forceinline__ void gload_lds16(const void* g, void* l) {
  __builtin_amdgcn_global_load_lds(
      (const __attribute__((address_space(1))) unsigned int*)g,
      (__attribute__((address_space(3))) unsigned int*)l, 16, 0, 0);
}

// ---------------------------------------------------------------------------
// 256^2 NT-GEMM core, 512 threads (8 waves, 2x4 wave grid: each wave owns a
// 128x64 quadrant = 8x4 frags of 16x16x32 MFMA -> 64 MFMA per K64-step per
// wave vs 8 staging issues: 2x the MFMA density of the 128^2 core).
// Double-buffered 2-phase: issue next tile's global_load_lds BEFORE compute,
// single __syncthreads() per K-step drains it after ~64-MFMA worth of cover.
// LDS: [buf][A 32KiB | B 32KiB] x2 = 128 KiB. XOR source-pre-swizzle (row&7)
// keeps the b128 fragment reads bank-conflict-free (both-sides-or-neither).
// ---------------------------------------------------------------------------
template <int RS, int KLEN>
__device__ __forceinline__ void nt_gemm256(const unsigned short* __restrict__ aB,
                                           const unsigned short* __restrict__ bB,
                                           f32x4 acc[8][4],
                                           unsigned short* lds) {
  const int tid  = threadIdx.x;
  const int wid  = tid >> 6;          // 0..7
  const int lane = tid & 63;
  const int wr   = (wid >> 2) * 128;  // wave row base within 256
  const int wc   = (wid & 3) * 64;    // wave col base within 256

  const f32x4 zero = {0.f, 0.f, 0.f, 0.f};
#pragma unroll
  for (int i = 0; i < 8; ++i)
#pragma unroll
    for (int j = 0; j < 4; ++j) acc[i][j] = zero;

  const int srow = lane >> 3;                 // 0..7: row within 8-row issue
  const int gsrc = (lane & 7) ^ srow;         // source chunk pre-swizzle
  constexpr int NT = KLEN / 64;

  auto stage = [&](int bf, int k0) {
#pragma unroll
    for (int i = 0; i < 4; ++i) {
      const int issue = wid * 4 + i;          // 0..31
      const int row   = issue * 8 + srow;     // 0..255
      const size_t go = (size_t)row * RS + k0 + gsrc * 8;
      gload_lds16(aB + go, lds + bf * 32768 + issue * 512);
      gload_lds16(bB + go, lds + bf * 32768 + 16384 + issue * 512);
    }
  };
  auto compute = [&](int bf) {
    const unsigned short* lA = lds + bf * 32768;
    const unsigned short* lB = lA + 16384;
#pragma unroll
    for (int s = 0; s < 2; ++s) {
      bf16x8 af[8], bfr[4];
#pragma unroll
      for (int mf = 0; mf < 8; ++mf) {
        const int row = wr + mf * 16 + (lane & 15);
        const int ch  = (s * 4 + (lane >> 4)) ^ (row & 7);
        af[mf] = *(const bf16x8*)(lA + row * 64 + ch * 8);
      }
#pragma unroll
      for (int nf = 0; nf < 4; ++nf) {
        const int row = wc + nf * 16 + (lane & 15);
        const int ch  = (s * 4 + (lane >> 4)) ^ (row & 7);
        bfr[nf] = *(const bf16x8*)(lB + row * 64 + ch * 8);
      }
#pragma unroll
      for (int mf = 0; mf < 8; ++mf)
#pragma unroll
        for (int nf = 0; nf < 4; ++nf)
          acc[mf][nf] = __builtin_amdgcn_mfma_f32_16x16x32_bf16(
              af[mf], bfr[nf], acc[mf][nf], 0, 0, 0);
    }
  };

  stage(0, 0);
  __syncthreads();                 // prologue drain
  int cur = 0;
#pragma unroll 1
  for (int t = 0; t < NT; ++t) {
    if (t + 1 < NT) stage(cur ^ 1, (t + 1) * 64);   // prefetch next tile
    compute(cur);                                    // MFMA on current
    __syncthreads();               // drains prefetch vmcnt after compute
    cur ^= 1;
  }
}

// ---------------------------------------------------------------------------
// K1: f32 input -> bf16 A16[b][n][c] (ws) + transposed AT16[b][c][n] (d_out
// scratch). 64x64 tiles; 4x4 register micro-tile transpose; LDS b64 only.
// ---------------------------------------------------------------------------
__global__ __launch_bounds__(256) void k_convert(const float* __restrict__ in,
                                                 unsigned short* __restrict__ a16,
                                                 unsigned short* __restrict__ at16) {
  __shared__ unsigned short lt[64 * 68];      // [c][n], row stride 68 ushorts
  const int b  = blockIdx.y;
  const int tn = blockIdx.x >> 3, tc = blockIdx.x & 7;
  const int n0 = tn * 64, c0 = tc * 64;
  const int t   = threadIdx.x;
  const int ctc = t & 15;                     // c-quad index (0..15)
  const int ntq = t >> 4;                     // n-quad index (0..15)

  const float* src = in + ((size_t)b * NN + n0 + 4 * ntq) * CC + c0 + 4 * ctc;
  unsigned short* adst = a16 + ((size_t)b * NN + n0 + 4 * ntq) * CC + c0 + 4 * ctc;

  unsigned short ob[4][4];                    // [n-local][c-local]
#pragma unroll
  for (int j = 0; j < 4; ++j) {
    float4 v = *(const float4*)(src + (size_t)j * CC);
    ob[j][0] = to_bf16(v.x); ob[j][1] = to_bf16(v.y);
    ob[j][2] = to_bf16(v.z); ob[j][3] = to_bf16(v.w);
    ushort4 o = {ob[j][0], ob[j][1], ob[j][2], ob[j][3]};
    *(ushort4*)(adst + (size_t)j * CC) = o;   // 128B contiguous per 16 lanes
  }
#pragma unroll
  for (int q = 0; q < 4; ++q) {
    ushort4 w = {ob[0][q], ob[1][q], ob[2][q], ob[3][q]};
    *(ushort4*)&lt[(4 * ctc + q) * 68 + 4 * ntq] = w;
  }
  __syncthreads();

  const int c_l = t >> 2, w4 = t & 3;
  const unsigned short* lr = lt + c_l * 68;
  uint2 r0a = *(const uint2*)(lr + 8 * w4);
  uint2 r0b = *(const uint2*)(lr + 8 * w4 + 4);
  uint2 r1a = *(const uint2*)(lr + 8 * w4 + 32);
  uint2 r1b = *(const uint2*)(lr + 8 * w4 + 36);
  unsigned short* tb = at16 + ((size_t)b * CC + c0 + c_l) * NN + n0;
  uint4 s0 = {r0a.x, r0a.y, r0b.x, r0b.y};
  uint4 s1 = {r1a.x, r1a.y, r1b.x, r1b.y};
  *(uint4*)(tb + 8 * w4)      = s0;           // 64B contiguous per 4 lanes
  *(uint4*)(tb + 8 * w4 + 32) = s1;
}

// ---------------------------------------------------------------------------
// K2: split-K Gram partials, 256^2 tiles. parts[ks][b][c][d], ks=0..3.
// Grid 256 = 16 b x 4 tiles x 4 ks -> exactly 1 block/CU. XCD-chunked
// swizzle, ks-outer within batch so the 4 same-ks tiles share their
// 512 KiB k-panels in the XCD's L2.
// ---------------------------------------------------------------------------
__global__ __launch_bounds__(512, 1) void k_gram(const unsigned short* __restrict__ at,
                                                 float* __restrict__ parts) {
  __shared__ __align__(16) unsigned short lds[65536];   // 128 KiB
  const int bid  = blockIdx.x;
  const int work = (bid & 7) * 32 + (bid >> 3);   // chunked XCD swizzle (256%8==0)
  const int b    = work >> 4;                      // 16 works per batch
  const int r    = work & 15;
  const int ks   = r >> 2;                         // k-split 0..3 (outer)
  const int tile = r & 3;                          // 2x2 tile grid
  const int c0 = (tile & 1) * 256;
  const int d0 = (tile >> 1) * 256;
  const unsigned short* aB = at + ((size_t)b * CC + c0) * NN + ks * 1024;
  const unsigned short* bB = at + ((size_t)b * CC + d0) * NN + ks * 1024;
  f32x4 acc[8][4];
  nt_gemm256<NN, 1024>(aB, bB, acc, lds);

  const int lane = threadIdx.x & 63, wid = threadIdx.x >> 6;
  const int wr = (wid >> 2) * 128, wc = (wid & 3) * 64;
  float* gb = parts + (size_t)ks * PELEM + (size_t)b * CC * CC;
#pragma unroll
  for (int mf = 0; mf < 8; ++mf)
#pragma unroll
    for (int nf = 0; nf < 4; ++nf)
#pragma unroll
      for (int q = 0; q < 4; ++q) {
        const int row = c0 + wr + mf * 16 + (lane >> 4) * 4 + q;   // c
        const int col = d0 + wc + nf * 16 + (lane & 15);           // d
        gb[(size_t)row * CC + col] = acc[mf][nf][q];
      }
}

// ---------------------------------------------------------------------------
// K3: fused: sum 4 partials -> row max -> exp/sum -> bf16 softmax -> ST[d][c]
// (transposed write via XOR-swizzled LDS). 1 wave = 1 row at a time.
// ---------------------------------------------------------------------------
__global__ __launch_bounds__(256) void k_softmax(const float* __restrict__ parts,
                                                 unsigned short* __restrict__ st) {
  __shared__ unsigned short ls[32][512];      // [c-local][d], XOR-swizzled groups
  const int b  = blockIdx.x >> 4;
  const int cb = blockIdx.x & 15;             // 16 c-blocks of 32 rows
  const int wid = threadIdx.x >> 6, lane = threadIdx.x & 63;

#pragma unroll 1
  for (int i = 0; i < 8; ++i) {
    const int rl = wid * 8 + i;               // 0..31
    const int c  = cb * 32 + rl;
    const int r7 = rl & 7;
    const float* base = parts + ((size_t)b * CC + c) * CC;
    float4 v0 = {0.f, 0.f, 0.f, 0.f}, v1 = {0.f, 0.f, 0.f, 0.f};
#pragma unroll
    for (int p = 0; p < 4; ++p) {
      float4 a = *(const float4*)(base + (size_t)p * PELEM + lane * 4);
      float4 bq = *(const float4*)(base + (size_t)p * PELEM + 256 + lane * 4);
      v0.x += a.x; v0.y += a.y; v0.z += a.z; v0.w += a.w;
      v1.x += bq.x; v1.y += bq.y; v1.z += bq.z; v1.w += bq.w;
    }
    float m = fmaxf(fmaxf(fmaxf(v0.x, v0.y), fmaxf(v0.z, v0.w)),
                    fmaxf(fmaxf(v1.x, v1.y), fmaxf(v1.z, v1.w)));
#pragma unroll
    for (int off = 32; off > 0; off >>= 1) m = fmaxf(m, __shfl_xor(m, off));
    float e0 = expf(v0.x - m), e1 = expf(v0.y - m), e2 = expf(v0.z - m), e3 = expf(v0.w - m);
    float e4 = expf(v1.x - m), e5 = expf(v1.y - m), e6 = expf(v1.z - m), e7 = expf(v1.w - m);
    float s = e0 + e1 + e2 + e3 + e4 + e5 + e6 + e7;
#pragma unroll
    for (int off = 32; off > 0; off >>= 1) s += __shfl_xor(s, off);
    const float pinv = 1.0f / s;
    ushort4 o0, o1;
    o0.x = to_bf16(e0 * pinv); o0.y = to_bf16(e1 * pinv);
    o0.z = to_bf16(e2 * pinv); o0.w = to_bf16(e3 * pinv);
    o1.x = to_bf16(e4 * pinv); o1.y = to_bf16(e5 * pinv);
    o1.z = to_bf16(e6 * pinv); o1.w = to_bf16(e7 * pinv);
    *(ushort4*)&ls[rl][(lane ^ r7) << 2]         = o0;   // d-group XOR swizzle
    *(ushort4*)&ls[rl][256 + ((lane ^ r7) << 2)] = o1;
  }
  __syncthreads();

  // transposed write: thread t handles d = t and d = 256+t; 32 c's each
#pragma unroll 1
  for (int i = 0; i < 2; ++i) {
    const int d = i * 256 + threadIdx.x;
    unsigned int u[16];
#pragma unroll
    for (int k = 0; k < 16; ++k) {
      const int c0i = 2 * k, c1i = 2 * k + 1;
      const unsigned int lo = ls[c0i][(((d >> 2) ^ (c0i & 7)) << 2) | (d & 3)];
      const unsigned int hi = ls[c1i][(((d >> 2) ^ (c1i & 7)) << 2) | (d & 3)];
      u[k] = lo | (hi << 16);
    }
    unsigned short* dst = st + ((size_t)b * CC + d) * CC + cb * 32;
    uint4 w0 = {u[0], u[1], u[2], u[3]};
    uint4 w1 = {u[4], u[5], u[6], u[7]};
    uint4 w2 = {u[8], u[9], u[10], u[11]};
    uint4 w3 = {u[12], u[13], u[14], u[15]};
    *(uint4*)(dst + 0)  = w0;
    *(uint4*)(dst + 8)  = w1;
    *(uint4*)(dst + 16) = w2;
    *(uint4*)(dst + 24) = w3;
  }
}

// ---------------------------------------------------------------------------
// K4: out[b][n][d] = gamma * sum_c A[n][c]*S[c][d] + x[b][n][d]
//     256^2 NT-GEMM A16[n][c] x ST[d][c], K=512 in-block (8 K-steps);
//     residual from a16 (bf16, L2-hot). Grid 512 = 16 b x 16 mt x 2 nt,
//     nt-major XCD swizzle keeps each st panel L2-resident.
// ---------------------------------------------------------------------------
__global__ __launch_bounds__(512, 1) void k_out(const unsigned short* __restrict__ a16,
                                                const unsigned short* __restrict__ st,
                                                const float* __restrict__ gammap,
                                                float* __restrict__ outp) {
  __shared__ __align__(16) unsigned short lds[65536];   // 128 KiB
  const int bid  = blockIdx.x;
  const int work = (bid & 7) * 64 + (bid >> 3);   // chunked XCD swizzle (512%8==0)
  const int b    = work >> 5;                      // 32 works per batch
  const int r    = work & 31;
  const int nt   = r >> 4;                         // nt-major: st panel L2-hot
  const int mt   = r & 15;
  const int n0 = mt * 256, d0 = nt * 256;
  const unsigned short* aB = a16 + ((size_t)b * NN + n0) * CC;
  const unsigned short* bB = st + ((size_t)b * CC + d0) * CC;
  f32x4 acc[8][4];
  nt_gemm256<CC, CC>(aB, bB, acc, lds);

  const float g = gammap[0];
  const int lane = threadIdx.x & 63, wid = threadIdx.x >> 6;
  const int wr = (wid >> 2) * 128, wc = (wid & 3) * 64;
  const unsigned short* xr = a16 + ((size_t)b * NN + n0) * CC + d0;
  float* ob = outp + ((size_t)b * NN + n0) * CC + d0;
#pragma unroll
  for (int mf = 0; mf < 8; ++mf)
#pragma unroll
    for (int nf = 0; nf < 4; ++nf)
#pragma unroll
      for (int q = 0; q < 4; ++q) {
        const int row = wr + mf * 16 + (lane >> 4) * 4 + q;   // n within 256
        const int col = wc + nf * 16 + (lane & 15);           // d within 256
        const size_t off = (size_t)row * CC + col;
        ob[off] = fmaf(g, acc[mf][nf][q], bf16_to_f32(xr[off]));
      }
}

// ---------------------------------------------------------------------------
// Memory plan:
//   ws   [0,64MiB)   A16 bf16            (64 MiB)
//        [64,72MiB)  ST bf16             (8 MiB)     -> ws need: 72 MiB
//   d_out[0,64MiB)   AT16 bf16 scratch   (k_convert -> k_gram)
//        [64,128MiB) gram partials f32x4 (k_gram -> k_softmax)
//   k_out fully overwrites d_out with the final 128 MiB output.
// ---------------------------------------------------------------------------
extern "C" void kernel_launch(void* const* d_in, const int* in_sizes, int n_in,
                              void* d_out, int out_size, void* d_ws, size_t ws_size,
                              hipStream_t stream) {
  const float* in    = (const float*)d_in[0];
  const float* gamma = (const float*)d_in[1];
  float* outp = (float*)d_out;

  unsigned short* a16  = (unsigned short*)d_ws;
  unsigned short* stb  = (unsigned short*)((char*)d_ws + ((size_t)64 << 20));
  unsigned short* at16 = (unsigned short*)d_out;                      // [0,64MiB)
  float*          parts = (float*)((char*)d_out + ((size_t)64 << 20)); // [64,128MiB)

  k_convert<<<dim3(512, 16), 256, 0, stream>>>(in, a16, at16);
  k_gram<<<dim3(256), 512, 0, stream>>>(at16, parts);
  k_softmax<<<dim3(256), 256, 0, stream>>>(parts, stb);
  k_out<<<dim3(512), 512, 0, stream>>>(a16, stb, gamma, outp);
}